// Round 4
// baseline (634.400 us; speedup 1.0000x reference)
//
#include <hip/hip_runtime.h>

// PSEAD attention. Math: scores_p = P_p (s*QK^T) P_p^T ;
// out_bh = (sum_p softmax(scores_p) P_p) V
// Dtype-adaptive (fp32/bf16 inputs), all-bf16 MFMA pipeline.
// R10: persistent tiles with CORRECT vmcnt discipline. R9 failed because
// vmcnt is in-order: counted waits after the epilogue forced full epilogue
// store completion every phase (MfmaUtil 10%, write RMW blowup). Now each
// tile boundary does exactly one vmcnt(0)+barrier AFTER the epilogue, so the
// next tile's counted waits start from a clean counter. Steady-state loop is
// byte-identical to R8 (verified 127us QKV). Merged preprocess kept.

typedef unsigned short u16;
typedef unsigned int u32;
typedef __attribute__((ext_vector_type(8))) __bf16 bf16x8;
typedef __attribute__((ext_vector_type(4))) float f32x4;
typedef __attribute__((ext_vector_type(4))) u32 u32x4;
typedef __attribute__((ext_vector_type(4))) u16 u16x4;
typedef __attribute__((ext_vector_type(4))) float float4v;
typedef __attribute__((address_space(1))) void gvoid;
typedef __attribute__((address_space(3))) void svoid;

#define MFMA16(a, b, c) __builtin_amdgcn_mfma_f32_16x16x32_bf16(a, b, c, 0, 0, 0)

__device__ __forceinline__ u16 f2bf(float f) {
  u32 u = __builtin_bit_cast(u32, f);
  return (u16)((u + 0x7fffu + ((u >> 16) & 1u)) >> 16);
}
__device__ __forceinline__ float bf2f(u16 h) {
  u32 u = ((u32)h) << 16;
  return __builtin_bit_cast(float, u);
}
__device__ __forceinline__ float ld_bias(const void* p, int i, int isf32) {
  return isf32 ? ((const float*)p)[i] : bf2f(((const u16*)p)[i]);
}
__device__ __forceinline__ bf16x8 ld_frag(const u16* p) {
  u32x4 v = *reinterpret_cast<const u32x4*>(p);
  return __builtin_bit_cast(bf16x8, v);
}
// K=16 padded to K=32: lanes >= 32 supply zeros
__device__ __forceinline__ bf16x8 ld_frag_lo(const u16* p, int lane) {
  u32x4 v = {0u, 0u, 0u, 0u};
  if (lane < 32) v = *reinterpret_cast<const u32x4*>(p);
  return __builtin_bit_cast(bf16x8, v);
}
__device__ __forceinline__ void async16(const u16* g, u16* l) {
  __builtin_amdgcn_global_load_lds((gvoid*)g, (svoid*)l, 16, 0, 0);
}

// C-layout f32x4 -> bf16 fragment holding X-as-B-operand (== X^T-as-A-operand).
__device__ __forceinline__ bf16x8 c2frag(f32x4 v, int lane) {
  const u32 p01 = ((u32)f2bf(v[1]) << 16) | (u32)f2bf(v[0]);
  const u32 p23 = ((u32)f2bf(v[3]) << 16) | (u32)f2bf(v[2]);
  const int base = (lane & 15) + ((lane & 16) << 1);
  u32x4 o;
  o[0] = (u32)__shfl((int)p01, base);
  o[1] = (u32)__shfl((int)p23, base);
  o[2] = (u32)__shfl((int)p01, base + 16);
  o[3] = (u32)__shfl((int)p23, base + 16);
  if (lane >= 32) o = (u32x4){0u, 0u, 0u, 0u};
  return __builtin_bit_cast(bf16x8, o);
}

// --------- dtype detect: fp32 u32-exponents cluster in [64,191] -------------
__global__ __launch_bounds__(1024) void detect_dtype(const u32* __restrict__ x,
                                                     int* __restrict__ flag) {
  const int tid = threadIdx.x;
  int cnt = 0;
#pragma unroll
  for (int q = 0; q < 4; ++q) {
    const u32x4 v = ((const u32x4*)x)[q * 1024 + tid];
#pragma unroll
    for (int j = 0; j < 4; ++j) {
      const u32 e = (v[j] >> 23) & 0xffu;
      cnt += (e >= 64u && e <= 191u) ? 1 : 0;
    }
  }
  __shared__ int sred[16];
  for (int o = 32; o; o >>= 1) cnt += __shfl_down(cnt, o);
  if ((tid & 63) == 0) sred[tid >> 6] = cnt;
  __syncthreads();
  if (tid == 0) {
    int t = 0;
#pragma unroll
    for (int i = 0; i < 16; ++i) t += sred[i];
    flag[0] = (t > 8192) ? 1 : 0;  // 1 = fp32
  }
}

// --------- fused preprocess: x convert + 4x weight transpose-convert ---------
// blocks [0,16384): canonicalize x (coalesced float4/u16x4, 4 elems/thread)
// blocks [16384,20480): dst[n][k] = bf16(src[k][n]) 32x32 tile transpose
__global__ __launch_bounds__(256) void preprocess(
    const void* __restrict__ src_x, u16* __restrict__ dst_x,
    const void* __restrict__ w0, const void* __restrict__ w1,
    const void* __restrict__ w2, const void* __restrict__ w3,
    u16* __restrict__ d0, u16* __restrict__ d1, u16* __restrict__ d2,
    u16* __restrict__ d3, const int* __restrict__ flag) {
  __shared__ u16 tile[32][33];
  const int bid = blockIdx.x;
  const int tid = threadIdx.x;
  const int isf32 = *flag;
  if (bid < 16384) {
    const int i4 = bid * 256 + tid;  // 4 elems per thread
    if (isf32) {
      const float4v v = ((const float4v*)src_x)[i4];
      u16x4 o;
#pragma unroll
      for (int j = 0; j < 4; ++j) o[j] = f2bf(v[j]);
      ((u16x4*)dst_x)[i4] = o;
    } else {
      ((u16x4*)dst_x)[i4] = ((const u16x4*)src_x)[i4];
    }
  } else {
    const int r = bid - 16384;
    const int z = r >> 10;
    const void* src = (z == 0) ? w0 : (z == 1) ? w1 : (z == 2) ? w2 : w3;
    u16* dst = (z == 0) ? d0 : (z == 1) ? d1 : (z == 2) ? d2 : d3;
    const int tx = tid & 31;
    const int ty = (tid >> 5) * 4;
    const int bx = (r & 31) * 32;
    const int by = ((r >> 5) & 31) * 32;
#pragma unroll
    for (int q = 0; q < 4; ++q) {
      const int idx = (by + ty + q) * 1024 + bx + tx;
      tile[ty + q][tx] = isf32 ? f2bf(((const float*)src)[idx]) : ((const u16*)src)[idx];
    }
    __syncthreads();
#pragma unroll
    for (int q = 0; q < 4; ++q)
      dst[(bx + ty + q) * 1024 + by + tx] = tile[tx][ty + q];
  }
}

// ------------ 256x256x64 bf16 MFMA GEMM, 8-phase, persistent tiles -----------
// MODE 0 (TILES=3): X @ WtQKV^T -> Q[bh][j][64], K[bh][j][64], Vt[bh][64][16]
// MODE 1 (TILES=1): T @ WtO^T + bo -> out (fp32 or bf16 per flag)
// K = 1024: 16 K-tiles of 64, 2/iteration, 7 staged iters + 1 peel per tile.
// Persistent: block keeps m0; walks TILES consecutive n-tiles. Peel of tile t
// stages tile t+1's kt0/kt1 (A src identical; B src +256 rows). The epilogue
// then runs with those in flight, followed by ONE vmcnt(0)+barrier so the
// next tile's counted waits start from a clean counter (vmcnt is in-order;
// without the drain, counted waits would wait on epilogue stores - R9 bug).
// LDS (u16 offsets): buf0 A [0,16384) B [16384,32768); buf1 A/B +32768.
// Swizzle: physical 16B-granule g_phys holds logical g_phys ^ (row&7);
// applied via pre-swizzled global SOURCE (dest linear) + XOR on ds_read.
template <int MODE, int TILES>
__global__ __launch_bounds__(512, 2) void gemm256(
    const u16* __restrict__ X, const u16* __restrict__ Wt,
    const void* __restrict__ b0, const void* __restrict__ b1,
    const void* __restrict__ b2, void* __restrict__ o0, u16* __restrict__ o1,
    u16* __restrict__ o2, const int* __restrict__ flag) {
  __shared__ alignas(16) u16 sm[65536];  // 128 KiB
  const int tid = threadIdx.x;
  const int wave = tid >> 6, lane = tid & 63;
  const int fr = lane & 15, fq = lane >> 4;
  const int wm = wave >> 2, wn = wave & 3;  // 2 x 4 waves
  const int isf32 = *flag;

  // T1: bijective XCD swizzle (gridDim.x % 8 == 0 by construction)
  const int nwg = gridDim.x;
  const int per = nwg >> 3;
  const int bid = blockIdx.x;
  const int wg = (bid & 7) * per + (bid >> 3);
  const int m0 = (wg & 63) << 8;         // 64 M-tiles of 256
  const int ng0 = (wg >> 6) * TILES;     // first n-tile index for this block

  // ---- staging bases (global source pre-swizzled; LDS dest linear) ----
  const int gl = ((tid & 7) ^ ((tid >> 3) & 7)) * 8;  // logical granule col
  const u16* aS = X + (size_t)(m0 + (tid >> 3)) * 1024 + gl;
  const u16* bS0 = Wt + (size_t)(ng0 * 256 + (tid >> 3)) * 1024 + gl;
  u16* dA = sm + wave * 512;           // + BUF*32768 + H*8192 + i*4096
  u16* dB = sm + 16384 + wave * 512;

  // ---- ds_read bases (XOR-swizzled granule) ----
  const u16* aR = sm + (wm * 128 + fr) * 64;
  const u16* bR = sm + 16384 + (wn * 64 + fr) * 64;
  const int g0 = (fq ^ (fr & 7)) * 8;        // kh=0 granule byte/2 offset
  const int g1 = ((fq ^ (fr & 7)) ^ 4) * 8;  // kh=1

  f32x4 acc[2][4][4] = {};
  bf16x8 af[2][4][2], bf[4][2];

#define STG_A(BUF, H, KT)                                                     \
  do {                                                                        \
    async16(aS + (H * 128) * 1024 + (KT), dA + (BUF)*32768 + (H)*8192);       \
    async16(aS + (H * 128 + 64) * 1024 + (KT),                                \
            dA + (BUF)*32768 + (H)*8192 + 4096);                              \
  } while (0)
#define STG_B(SRC, BUF, H, KT)                                                \
  do {                                                                        \
    async16((SRC) + (H * 128) * 1024 + (KT), dB + (BUF)*32768 + (H)*8192);    \
    async16((SRC) + (H * 128 + 64) * 1024 + (KT),                             \
            dB + (BUF)*32768 + (H)*8192 + 4096);                              \
  } while (0)
#define LDA_ALL(CH, KH, BUF)                                                  \
  do {                                                                        \
    af[CH][0][KH] = ld_frag(aR + (BUF)*32768 + (CH)*4096 + ((KH) ? g1 : g0)); \
    af[CH][1][KH] =                                                           \
        ld_frag(aR + (BUF)*32768 + (CH)*4096 + 1024 + ((KH) ? g1 : g0));      \
    af[CH][2][KH] =                                                           \
        ld_frag(aR + (BUF)*32768 + (CH)*4096 + 2048 + ((KH) ? g1 : g0));      \
    af[CH][3][KH] =                                                           \
        ld_frag(aR + (BUF)*32768 + (CH)*4096 + 3072 + ((KH) ? g1 : g0));      \
  } while (0)
#define LDB_ALL(KH, BUF)                                                      \
  do {                                                                        \
    bf[0][KH] = ld_frag(bR + (BUF)*32768 + ((KH) ? g1 : g0));                 \
    bf[1][KH] = ld_frag(bR + (BUF)*32768 + 1024 + ((KH) ? g1 : g0));          \
    bf[2][KH] = ld_frag(bR + (BUF)*32768 + 2048 + ((KH) ? g1 : g0));          \
    bf[3][KH] = ld_frag(bR + (BUF)*32768 + 3072 + ((KH) ? g1 : g0));          \
  } while (0)
#define MM1(CH, FI, KH)                                                       \
  acc[CH][FI][0] = MFMA16(af[CH][FI][KH], bf[0][KH], acc[CH][FI][0]);         \
  acc[CH][FI][1] = MFMA16(af[CH][FI][KH], bf[1][KH], acc[CH][FI][1]);         \
  acc[CH][FI][2] = MFMA16(af[CH][FI][KH], bf[2][KH], acc[CH][FI][2]);         \
  acc[CH][FI][3] = MFMA16(af[CH][FI][KH], bf[3][KH], acc[CH][FI][3]);
#define MM(CH, KH)                                                            \
  do {                                                                        \
    __builtin_amdgcn_s_setprio(1);                                            \
    MM1(CH, 0, KH) MM1(CH, 1, KH) MM1(CH, 2, KH) MM1(CH, 3, KH)               \
    __builtin_amdgcn_s_setprio(0);                                            \
  } while (0)
#define BARR                                                                  \
  __builtin_amdgcn_s_barrier();                                               \
  __builtin_amdgcn_sched_barrier(0)
#define WAITV_IMM(N) asm volatile("s_waitcnt vmcnt(" #N ")" ::: "memory")
#define WAITV(N) WAITV_IMM(N)
#define WAITL asm volatile("s_waitcnt lgkmcnt(0)" ::: "memory")
#define SCHED __builtin_amdgcn_sched_barrier(0)

  // One iteration: compute buf0 (P1-P4) + buf1 (P5-P8); stage the NEXT pair
  // (same tile: kof+128/kof+192; peel: next tile's kt0/kt1 via AKA..BKB).
  // Waits: end-P4 vmcnt(8) (buf1 batch retired; issued >=4 phases prior),
  // end-P8 vmcnt(8) (buf0-next batch retired). STG=0 (final peel) drains.
#define PHASES(STG, BSRC, AKA, AKB, BKA, BKB)                                 \
  do {                                                                        \
    /* P1 */                                                                  \
    LDA_ALL(0, 0, 0);                                                         \
    LDB_ALL(0, 0);                                                            \
    LDA_ALL(1, 0, 0);                                                         \
    BARR;                                                                     \
    MM(0, 0);                                                                 \
    BARR;                                                                     \
    /* P2: WAITL frees buf0-A */                                              \
    LDA_ALL(0, 1, 0);                                                         \
    LDA_ALL(1, 1, 0);                                                         \
    BARR;                                                                     \
    MM(1, 0);                                                                 \
    WAITL;                                                                    \
    SCHED;                                                                    \
    BARR;                                                                     \
    /* P3: buf0-A free -> stage A0h0 */                                       \
    LDB_ALL(1, 0);                                                            \
    if (STG) STG_A(0, 0, AKA);                                                \
    BARR;                                                                     \
    MM(0, 1);                                                                 \
    BARR;                                                                     \
    /* P4: buf0-B free -> stage A0h1,B0; counted wait for buf1 batch */       \
    if (STG) {                                                                \
      STG_A(0, 1, AKA);                                                       \
      STG_B(BSRC, 0, 0, BKA);                                                 \
      STG_B(BSRC, 0, 1, BKA);                                                 \
    }                                                                         \
    BARR;                                                                     \
    MM(1, 1);                                                                 \
    if (STG) {                                                                \
      WAITV(8);                                                               \
    } else {                                                                  \
      WAITV(0);                                                               \
    }                                                                         \
    SCHED;                                                                    \
    BARR;                                                                     \
    /* P5 */                                                                  \
    LDA_ALL(0, 0, 1);                                                         \
    LDB_ALL(0, 1);                                                            \
    LDA_ALL(1, 0, 1);                                                         \
    BARR;                                                                     \
    MM(0, 0);                                                                 \
    BARR;                                                                     \
    /* P6: WAITL frees buf1-A */                                              \
    LDA_ALL(0, 1, 1);                                                         \
    LDA_ALL(1, 1, 1);                                                         \
    BARR;                                                                     \
    MM(1, 0);                                                                 \
    WAITL;                                                                    \
    SCHED;                                                                    \
    BARR;                                                                     \
    /* P7: buf1-A free -> stage A1h0 */                                       \
    LDB_ALL(1, 1);                                                            \
    if (STG) STG_A(1, 0, AKB);                                                \
    BARR;                                                                     \
    MM(0, 1);                                                                 \
    BARR;                                                                     \
    /* P8: buf1-B free -> stage A1h1,B1; counted wait for buf0-next batch */  \
    if (STG) {                                                                \
      STG_A(1, 1, AKB);                                                       \
      STG_B(BSRC, 1, 0, BKB);                                                 \
      STG_B(BSRC, 1, 1, BKB);                                                 \
    }                                                                         \
    BARR;                                                                     \
    MM(1, 1);                                                                 \
    if (STG) {                                                                \
      WAITV(8);                                                               \
      SCHED;                                                                  \
    }                                                                         \
    BARR;                                                                     \
  } while (0)

  // ---- prologue: stage tile-0 kt0+kt1 in steady-state order; land kt0 ----
  STG_A(0, 0, 0);
  STG_A(0, 1, 0);
  STG_B(bS0, 0, 0, 0);
  STG_B(bS0, 0, 1, 0);
  STG_A(1, 0, 64);
  STG_A(1, 1, 64);
  STG_B(bS0, 1, 0, 64);
  STG_B(bS0, 1, 1, 64);
  WAITV(8);
  BARR;

#pragma unroll 1
  for (int t = 0; t < TILES; ++t) {
    const u16* bSt = bS0 + (size_t)t * 256 * 1024;
    const u16* bSn = bSt + 256 * 1024;  // next tile's B source (guarded use)
    // ---- main loop: it computes kt 2it,2it+1; stages kt 2it+2,2it+3 ----
    for (int it = 0; it < 7; ++it) {
      const int kof = it * 128;
      PHASES(1, bSt, kof + 128, kof + 192, kof + 128, kof + 192);
    }
    // ---- peel: kt14 (buf0), kt15 (buf1); stage next tile's kt0/kt1 ----
    if (t + 1 < TILES) {
      PHASES(1, bSn, 0, 64, 0, 64);
    } else {
      PHASES(0, bSt, 0, 64, 0, 64);
    }

    // ---- epilogue (no LDS use; overlaps the in-flight staging loads) ----
    const int n0 = (ng0 + t) << 8;
    if constexpr (MODE == 0) {
      const int q = n0 >> 10;  // 0=Q,1=K,2=V
      const int nb = (n0 & 1023) + wn * 64;
      const void* bp = (q == 0) ? b0 : ((q == 1) ? b1 : b2);
      u16* q0 = (u16*)o0;
#pragma unroll
      for (int ch = 0; ch < 2; ++ch)
#pragma unroll
        for (int fi = 0; fi < 4; ++fi) {
          const int mbase = m0 + wm * 128 + ch * 64 + fi * 16;  // mult of 16
          const int bidx = mbase >> 4;
#pragma unroll
          for (int bj = 0; bj < 4; ++bj) {
            const int nl = nb + bj * 16 + fr;
            const int h = nl >> 6, d = nl & 63;
            const float bias = ld_bias(bp, nl, isf32);
            const int bh = bidx * 16 + h;
            if (q == 2) {
              u16x4 pk;
#pragma unroll
              for (int r = 0; r < 4; ++r) pk[r] = f2bf(acc[ch][fi][bj][r] + bias);
              *reinterpret_cast<u16x4*>(&o2[(bh * 64 + d) * 16 + fq * 4]) = pk;
            } else {
              u16* dstq = (q == 0) ? q0 : o1;
#pragma unroll
              for (int r = 0; r < 4; ++r)
                dstq[(bh * 16 + fq * 4 + r) * 64 + d] =
                    f2bf(acc[ch][fi][bj][r] + bias);
            }
          }
        }
    } else {
#pragma unroll
      for (int ch = 0; ch < 2; ++ch)
#pragma unroll
        for (int fi = 0; fi < 4; ++fi) {
          const int m = m0 + wm * 128 + ch * 64 + fi * 16 + fq * 4;
#pragma unroll
          for (int bj = 0; bj < 4; ++bj) {
            const int n = n0 + wn * 64 + bj * 16 + fr;
            const float bias = ld_bias(b0, n, isf32);
            if (isf32) {
#pragma unroll
              for (int r = 0; r < 4; ++r)
                ((float*)o0)[(m + r) * 1024 + n] = acc[ch][fi][bj][r] + bias;
            } else {
#pragma unroll
              for (int r = 0; r < 4; ++r)
                ((u16*)o0)[(m + r) * 1024 + n] = f2bf(acc[ch][fi][bj][r] + bias);
            }
          }
        }
    }
    // ---- boundary drain: retire epilogue VMEM (and landed staging) so the
    // next tile's counted waits see a clean in-order counter (R9 bug fix) ----
    if (t + 1 < TILES) {
      WAITV(0);
      SCHED;
      BARR;
#pragma unroll
      for (int a1 = 0; a1 < 2; ++a1)
#pragma unroll
        for (int a2 = 0; a2 < 4; ++a2)
#pragma unroll
          for (int a3 = 0; a3 < 4; ++a3)
            acc[a1][a2][a3] = (f32x4){0.f, 0.f, 0.f, 0.f};
    }
  }
#undef STG_A
#undef STG_B
#undef LDA_ALL
#undef LDB_ALL
#undef MM1
#undef MM
#undef BARR
#undef WAITV_IMM
#undef WAITV
#undef WAITL
#undef SCHED
#undef PHASES
}

// ---------------- attention: one wave per (b,h), transposed chain ------------
// All operand transforms are register shuffles (c2frag), no LDS round-trips.
__global__ __launch_bounds__(256) void attn_kernel(
    const u16* __restrict__ Qb, const u16* __restrict__ Kb, const u16* __restrict__ Vt,
    const void* __restrict__ P, u16* __restrict__ Tb,
    const int* __restrict__ flag) {
  __shared__ alignas(16) u16 Pl[4096];   // P[p][i][j]
  __shared__ alignas(16) u16 Ptl[4096];  // P^T
  const int tid = threadIdx.x;
  const int isf32 = *flag;
#pragma unroll
  for (int i = 0; i < 16; ++i) {
    const int idx = i * 256 + tid;
    const u16 v = isf32 ? f2bf(((const float*)P)[idx]) : ((const u16*)P)[idx];
    Pl[idx] = v;
    const int p = idx >> 8, rc = idx & 255, rr = rc >> 4, cc = rc & 15;
    Ptl[(p << 8) + (cc << 4) + rr] = v;
  }
  __syncthreads();

  const int wave = tid >> 6, lane = tid & 63;
  const int bh = blockIdx.x * 4 + wave;
  const int fr = lane & 15, fq = lane >> 4;

  const u16* qb = Qb + bh * 1024;
  const u16* kb = Kb + bh * 1024;
  const u16* vb = Vt + bh * 1024;

  const bf16x8 qf0 = ld_frag(qb + fr * 64 + fq * 8);
  const bf16x8 qf1 = ld_frag(qb + fr * 64 + 32 + fq * 8);
  const bf16x8 kf0 = ld_frag(kb + fr * 64 + fq * 8);
  const bf16x8 kf1 = ld_frag(kb + fr * 64 + 32 + fq * 8);
  f32x4 S = {0.f, 0.f, 0.f, 0.f};
  S = MFMA16(qf0, kf0, S);
  S = MFMA16(qf1, kf1, S);
#pragma unroll
  for (int r = 0; r < 4; ++r) S[r] *= 0.125f;  // 1/sqrt(64)
  const bf16x8 St = c2frag(S, lane);  // S^T as A-operand, reused all irreps

  f32x4 Mt = {0.f, 0.f, 0.f, 0.f};
#pragma unroll 4
  for (int p = 0; p < 16; ++p) {
    const bf16x8 pl = ld_frag_lo(Pl + (p << 8) + fr * 16 + fq * 8, lane);
    const bf16x8 pt = ld_frag_lo(Ptl + (p << 8) + fr * 16 + fq * 8, lane);
    f32x4 z = {0.f, 0.f, 0.f, 0.f};
    const f32x4 ApT = MFMA16(St, pl, z);                 // (P_p S)^T
    const f32x4 BpT = MFMA16(pl, c2frag(ApT, lane), z);  // scores^T
    float e[4], s = 0.f;
#pragma unroll
    for (int r = 0; r < 4; ++r) {
      e[r] = __expf(BpT[r]);
      s += e[r];
    }
    s += __shfl_xor(s, 16);
    s += __shfl_xor(s, 32);
    const float rs = __frcp_rn(s);
    f32x4 w;
#pragma unroll
    for (int r = 0; r < 4; ++r) w[r] = e[r] * rs;
    Mt = MFMA16(pt, c2frag(w, lane), Mt);  // (w P_p)^T accumulated
  }

  const bf16x8 mb = c2frag(Mt, lane);  // M^T as B-operand

  const int b = bh >> 4, h = bh & 15;
  u16* outp = Tb + (b * 16 + fr) * 1024 + h * 64;  // fr = i (C-layout col)
#pragma unroll
  for (int dt = 0; dt < 4; ++dt) {
    const bf16x8 vf = ld_frag_lo(vb + (dt * 16 + fr) * 16 + fq * 8, lane);
    f32x4 z = {0.f, 0.f, 0.f, 0.f};
    const f32x4 ot = MFMA16(vf, mb, z);  // O^T tile: row=d, col=i
    u16x4 pk;
#pragma unroll
    for (int r = 0; r < 4; ++r) pk[r] = f2bf(ot[r]);
    *reinterpret_cast<u16x4*>(&outp[dt * 16 + fq * 4]) = pk;
  }
}

// ---------------- launcher ---------------------------------------------------
extern "C" void kernel_launch(void* const* d_in, const int* in_sizes, int n_in,
                              void* d_out, int out_size, void* d_ws, size_t ws_size,
                              hipStream_t stream) {
  const void* x = d_in[0];
  const void* proj = d_in[1];
  const void* Wq = d_in[2];
  const void* bq = d_in[3];
  const void* Wk = d_in[4];
  const void* bk = d_in[5];
  const void* Wv = d_in[6];
  const void* bv = d_in[7];
  const void* Wo = d_in[8];
  const void* bo = d_in[9];

  char* ws = (char*)d_ws;
  int* flag = (int*)ws;          ws += 256;
  u16* WtQKV = (u16*)ws;         ws += (size_t)3072 * 1024 * 2;
  u16* WtO   = (u16*)ws;         ws += (size_t)1024 * 1024 * 2;
  u16* Xb    = (u16*)ws;         ws += (size_t)16384 * 1024 * 2;
  u16* Qbuf  = (u16*)ws;         ws += (size_t)16384 * 1024 * 2;
  u16* Kbuf  = (u16*)ws;         ws += (size_t)16384 * 1024 * 2;
  u16* Vtb   = (u16*)ws;         ws += (size_t)16384 * 1024 * 2;
  u16* Tbuf  = (u16*)ws;         ws += (size_t)16384 * 1024 * 2;

  detect_dtype<<<1, 1024, 0, stream>>>((const u32*)x, flag);
  preprocess<<<20480, 256, 0, stream>>>(
      x, Xb, Wq, Wk, Wv, Wo, WtQKV, WtQKV + 1024 * 1024,
      WtQKV + 2 * 1024 * 1024, WtO, flag);

  // QKV GEMM: M=16384, N=3072 -> 256 persistent blocks x 3 n-tiles
  gemm256<0, 3><<<dim3(256), 512, 0, stream>>>(
      Xb, WtQKV, bq, bk, bv, Qbuf, Kbuf, Vtb, flag);
  attn_kernel<<<4096, 256, 0, stream>>>(Qbuf, Kbuf, Vtb, proj, Tbuf, flag);
  // out GEMM: M=16384, N=1024 -> 256 blocks x 1 tile
  gemm256<1, 1><<<dim3(256), 512, 0, stream>>>(
      Tbuf, WtO, bo, nullptr, nullptr, d_out, nullptr, nullptr, flag);
}

// Round 5
// 346.812 us; speedup vs baseline: 1.8292x; 1.8292x over previous
//
#include <hip/hip_runtime.h>

// PSEAD attention. Math: scores_p = P_p (s*QK^T) P_p^T ;
// out_bh = (sum_p softmax(scores_p) P_p) V
// Dtype-adaptive (fp32/bf16 inputs), all-bf16 MFMA pipeline.
// R11: REVERT persistent tiling (R9/R10: 3.3x L2-miss traffic blowup,
// dur = bytes/2.5TB/s in all variants -> traffic-bound; mechanism is
// epilogue-write/staging interleave thrash). GEMMs restored to R7 exact
// (best measured: QKV 123.6us). Kept: merged preprocess (verified neutral).
// New: attn packs 2 irreps per Mt-accumulation MFMA (K=16+16=32), saving
// 8 of 54 MFMAs/wave -- Mt is a sum over irreps, so the MFMA K-sum fuses
// the pair; packed-A address reuses c2frag's lane-bit-0..4-only base.

typedef unsigned short u16;
typedef unsigned int u32;
typedef __attribute__((ext_vector_type(8))) __bf16 bf16x8;
typedef __attribute__((ext_vector_type(4))) float f32x4;
typedef __attribute__((ext_vector_type(4))) u32 u32x4;
typedef __attribute__((ext_vector_type(4))) u16 u16x4;
typedef __attribute__((ext_vector_type(4))) float float4v;
typedef __attribute__((address_space(1))) void gvoid;
typedef __attribute__((address_space(3))) void svoid;

#define MFMA16(a, b, c) __builtin_amdgcn_mfma_f32_16x16x32_bf16(a, b, c, 0, 0, 0)

__device__ __forceinline__ u16 f2bf(float f) {
  u32 u = __builtin_bit_cast(u32, f);
  return (u16)((u + 0x7fffu + ((u >> 16) & 1u)) >> 16);
}
__device__ __forceinline__ float bf2f(u16 h) {
  u32 u = ((u32)h) << 16;
  return __builtin_bit_cast(float, u);
}
__device__ __forceinline__ float ld_bias(const void* p, int i, int isf32) {
  return isf32 ? ((const float*)p)[i] : bf2f(((const u16*)p)[i]);
}
__device__ __forceinline__ bf16x8 ld_frag(const u16* p) {
  u32x4 v = *reinterpret_cast<const u32x4*>(p);
  return __builtin_bit_cast(bf16x8, v);
}
// K=16 padded to K=32: lanes >= 32 supply zeros
__device__ __forceinline__ bf16x8 ld_frag_lo(const u16* p, int lane) {
  u32x4 v = {0u, 0u, 0u, 0u};
  if (lane < 32) v = *reinterpret_cast<const u32x4*>(p);
  return __builtin_bit_cast(bf16x8, v);
}
__device__ __forceinline__ void async16(const u16* g, u16* l) {
  __builtin_amdgcn_global_load_lds((gvoid*)g, (svoid*)l, 16, 0, 0);
}

// C-layout f32x4 -> bf16 fragment holding X-as-B-operand (== X^T-as-A-operand).
__device__ __forceinline__ bf16x8 c2frag(f32x4 v, int lane) {
  const u32 p01 = ((u32)f2bf(v[1]) << 16) | (u32)f2bf(v[0]);
  const u32 p23 = ((u32)f2bf(v[3]) << 16) | (u32)f2bf(v[2]);
  const int base = (lane & 15) + ((lane & 16) << 1);
  u32x4 o;
  o[0] = (u32)__shfl((int)p01, base);
  o[1] = (u32)__shfl((int)p23, base);
  o[2] = (u32)__shfl((int)p01, base + 16);
  o[3] = (u32)__shfl((int)p23, base + 16);
  if (lane >= 32) o = (u32x4){0u, 0u, 0u, 0u};
  return __builtin_bit_cast(bf16x8, o);
}

// Packed pair: lanes 0..31 hold va's fragment (k=0..15), lanes 32..63 hold
// vb's fragment (k=16..31). base uses only lane bits 0..4, so lanes >=32
// reproduce their (lane-32) twin's gather on vb's words.
__device__ __forceinline__ bf16x8 c2frag_pair(f32x4 va, f32x4 vb, int lane) {
  const u32 a01 = ((u32)f2bf(va[1]) << 16) | (u32)f2bf(va[0]);
  const u32 a23 = ((u32)f2bf(va[3]) << 16) | (u32)f2bf(va[2]);
  const u32 b01 = ((u32)f2bf(vb[1]) << 16) | (u32)f2bf(vb[0]);
  const u32 b23 = ((u32)f2bf(vb[3]) << 16) | (u32)f2bf(vb[2]);
  const int base = (lane & 15) + ((lane & 16) << 1);
  const u32 sa0 = (u32)__shfl((int)a01, base);
  const u32 sa1 = (u32)__shfl((int)a23, base);
  const u32 sa2 = (u32)__shfl((int)a01, base + 16);
  const u32 sa3 = (u32)__shfl((int)a23, base + 16);
  const u32 sb0 = (u32)__shfl((int)b01, base);
  const u32 sb1 = (u32)__shfl((int)b23, base);
  const u32 sb2 = (u32)__shfl((int)b01, base + 16);
  const u32 sb3 = (u32)__shfl((int)b23, base + 16);
  u32x4 o;
  o[0] = (lane < 32) ? sa0 : sb0;
  o[1] = (lane < 32) ? sa1 : sb1;
  o[2] = (lane < 32) ? sa2 : sb2;
  o[3] = (lane < 32) ? sa3 : sb3;
  return __builtin_bit_cast(bf16x8, o);
}

// --------- dtype detect: fp32 u32-exponents cluster in [64,191] -------------
__global__ __launch_bounds__(1024) void detect_dtype(const u32* __restrict__ x,
                                                     int* __restrict__ flag) {
  const int tid = threadIdx.x;
  int cnt = 0;
#pragma unroll
  for (int q = 0; q < 4; ++q) {
    const u32x4 v = ((const u32x4*)x)[q * 1024 + tid];
#pragma unroll
    for (int j = 0; j < 4; ++j) {
      const u32 e = (v[j] >> 23) & 0xffu;
      cnt += (e >= 64u && e <= 191u) ? 1 : 0;
    }
  }
  __shared__ int sred[16];
  for (int o = 32; o; o >>= 1) cnt += __shfl_down(cnt, o);
  if ((tid & 63) == 0) sred[tid >> 6] = cnt;
  __syncthreads();
  if (tid == 0) {
    int t = 0;
#pragma unroll
    for (int i = 0; i < 16; ++i) t += sred[i];
    flag[0] = (t > 8192) ? 1 : 0;  // 1 = fp32
  }
}

// --------- fused preprocess: x convert + 4x weight transpose-convert ---------
// blocks [0,16384): canonicalize x (coalesced float4/u16x4, 4 elems/thread)
// blocks [16384,20480): dst[n][k] = bf16(src[k][n]) 32x32 tile transpose
__global__ __launch_bounds__(256) void preprocess(
    const void* __restrict__ src_x, u16* __restrict__ dst_x,
    const void* __restrict__ w0, const void* __restrict__ w1,
    const void* __restrict__ w2, const void* __restrict__ w3,
    u16* __restrict__ d0, u16* __restrict__ d1, u16* __restrict__ d2,
    u16* __restrict__ d3, const int* __restrict__ flag) {
  __shared__ u16 tile[32][33];
  const int bid = blockIdx.x;
  const int tid = threadIdx.x;
  const int isf32 = *flag;
  if (bid < 16384) {
    const int i4 = bid * 256 + tid;  // 4 elems per thread
    if (isf32) {
      const float4v v = ((const float4v*)src_x)[i4];
      u16x4 o;
#pragma unroll
      for (int j = 0; j < 4; ++j) o[j] = f2bf(v[j]);
      ((u16x4*)dst_x)[i4] = o;
    } else {
      ((u16x4*)dst_x)[i4] = ((const u16x4*)src_x)[i4];
    }
  } else {
    const int r = bid - 16384;
    const int z = r >> 10;
    const void* src = (z == 0) ? w0 : (z == 1) ? w1 : (z == 2) ? w2 : w3;
    u16* dst = (z == 0) ? d0 : (z == 1) ? d1 : (z == 2) ? d2 : d3;
    const int tx = tid & 31;
    const int ty = (tid >> 5) * 4;
    const int bx = (r & 31) * 32;
    const int by = ((r >> 5) & 31) * 32;
#pragma unroll
    for (int q = 0; q < 4; ++q) {
      const int idx = (by + ty + q) * 1024 + bx + tx;
      tile[ty + q][tx] = isf32 ? f2bf(((const float*)src)[idx]) : ((const u16*)src)[idx];
    }
    __syncthreads();
#pragma unroll
    for (int q = 0; q < 4; ++q)
      dst[(bx + ty + q) * 1024 + by + tx] = tile[tx][ty + q];
  }
}

// ---------------- 256x256x64 bf16 MFMA GEMM, 8-phase schedule ----------------
// MODE 0: X @ WtQKV^T -> Q[bh][j][64], K[bh][j][64], Vt[bh][64][16]
// MODE 1: T @ WtO^T + bo -> out (fp32 or bf16 per flag)
// K = 1024 fixed: 16 K-tiles of 64, 2 per iteration, 7 iters + peeled last.
// LDS (u16 offsets): buf0 A [0,16384) B [16384,32768); buf1 A/B +32768.
// Swizzle: physical 16B-granule g_phys holds logical g_phys ^ (row&7);
// applied via pre-swizzled global SOURCE (dest linear) + XOR on ds_read.
// (R7 schedule, best measured: QKV 123.6us.)
template <int MODE>
__global__ __launch_bounds__(512, 2) void gemm256(
    const u16* __restrict__ X, const u16* __restrict__ Wt,
    const void* __restrict__ b0, const void* __restrict__ b1,
    const void* __restrict__ b2, void* __restrict__ o0, u16* __restrict__ o1,
    u16* __restrict__ o2, const int* __restrict__ flag) {
  __shared__ alignas(16) u16 sm[65536];  // 128 KiB
  const int tid = threadIdx.x;
  const int wave = tid >> 6, lane = tid & 63;
  const int fr = lane & 15, fq = lane >> 4;
  const int wm = wave >> 2, wn = wave & 3;  // 2 x 4 waves
  const int isf32 = *flag;

  // T1: bijective XCD swizzle (gridDim.x % 8 == 0 by construction)
  const int nwg = gridDim.x;
  const int per = nwg >> 3;
  const int bid = blockIdx.x;
  const int wg = (bid & 7) * per + (bid >> 3);
  const int m0 = (wg & 63) << 8;  // 64 M-tiles of 256
  const int n0 = (wg >> 6) << 8;

  // ---- staging bases (global source pre-swizzled; LDS dest linear) ----
  const int gl = ((tid & 7) ^ ((tid >> 3) & 7)) * 8;  // logical granule col
  const u16* aS = X + (size_t)(m0 + (tid >> 3)) * 1024 + gl;
  const u16* bS = Wt + (size_t)(n0 + (tid >> 3)) * 1024 + gl;
  u16* dA = sm + wave * 512;           // + BUF*32768 + H*8192 + i*4096
  u16* dB = sm + 16384 + wave * 512;

  // ---- ds_read bases (XOR-swizzled granule) ----
  const u16* aR = sm + (wm * 128 + fr) * 64;
  const u16* bR = sm + 16384 + (wn * 64 + fr) * 64;
  const int g0 = (fq ^ (fr & 7)) * 8;        // kh=0 granule byte/2 offset
  const int g1 = ((fq ^ (fr & 7)) ^ 4) * 8;  // kh=1

  f32x4 acc[4][4] = {};
  f32x4 acc2[4][4] = {};
  bf16x8 af[2][4][2], bf[4][2];

#define ACC(CH, FI, BJ) ((CH) ? acc2[FI][BJ] : acc[FI][BJ])
#define STG_A(BUF, H, KT)                                                     \
  do {                                                                        \
    async16(aS + (H * 128) * 1024 + (KT), dA + (BUF)*32768 + (H)*8192);       \
    async16(aS + (H * 128 + 64) * 1024 + (KT),                                \
            dA + (BUF)*32768 + (H)*8192 + 4096);                              \
  } while (0)
#define STG_B(BUF, H, KT)                                                     \
  do {                                                                        \
    async16(bS + (H * 128) * 1024 + (KT), dB + (BUF)*32768 + (H)*8192);       \
    async16(bS + (H * 128 + 64) * 1024 + (KT),                                \
            dB + (BUF)*32768 + (H)*8192 + 4096);                              \
  } while (0)
#define LDA_ALL(CH, KH, BUF)                                                  \
  do {                                                                        \
    af[CH][0][KH] = ld_frag(aR + (BUF)*32768 + (CH)*4096 + ((KH) ? g1 : g0)); \
    af[CH][1][KH] =                                                           \
        ld_frag(aR + (BUF)*32768 + (CH)*4096 + 1024 + ((KH) ? g1 : g0));      \
    af[CH][2][KH] =                                                           \
        ld_frag(aR + (BUF)*32768 + (CH)*4096 + 2048 + ((KH) ? g1 : g0));      \
    af[CH][3][KH] =                                                           \
        ld_frag(aR + (BUF)*32768 + (CH)*4096 + 3072 + ((KH) ? g1 : g0));      \
  } while (0)
#define LDB_ALL(KH, BUF)                                                      \
  do {                                                                        \
    bf[0][KH] = ld_frag(bR + (BUF)*32768 + ((KH) ? g1 : g0));                 \
    bf[1][KH] = ld_frag(bR + (BUF)*32768 + 1024 + ((KH) ? g1 : g0));          \
    bf[2][KH] = ld_frag(bR + (BUF)*32768 + 2048 + ((KH) ? g1 : g0));          \
    bf[3][KH] = ld_frag(bR + (BUF)*32768 + 3072 + ((KH) ? g1 : g0));          \
  } while (0)
#define MM1(CH, FI, KH)                                                       \
  ACC(CH, FI, 0) = MFMA16(af[CH][FI][KH], bf[0][KH], ACC(CH, FI, 0));         \
  ACC(CH, FI, 1) = MFMA16(af[CH][FI][KH], bf[1][KH], ACC(CH, FI, 1));         \
  ACC(CH, FI, 2) = MFMA16(af[CH][FI][KH], bf[2][KH], ACC(CH, FI, 2));         \
  ACC(CH, FI, 3) = MFMA16(af[CH][FI][KH], bf[3][KH], ACC(CH, FI, 3));
#define MM(CH, KH)                                                            \
  do {                                                                        \
    __builtin_amdgcn_s_setprio(1);                                            \
    MM1(CH, 0, KH) MM1(CH, 1, KH) MM1(CH, 2, KH) MM1(CH, 3, KH)               \
    __builtin_amdgcn_s_setprio(0);                                            \
  } while (0)
#define BARR                                                                  \
  __builtin_amdgcn_s_barrier();                                               \
  __builtin_amdgcn_sched_barrier(0)
#define WAITV(N) asm volatile("s_waitcnt vmcnt(" #N ")" ::: "memory")
#define WAITL asm volatile("s_waitcnt lgkmcnt(0)" ::: "memory")
#define SCHED __builtin_amdgcn_sched_barrier(0)

  // ---- prologue: kt0 full + kt1 A-halves; only kt1-A may stay in flight ----
  STG_A(0, 0, 0);
  STG_A(0, 1, 0);
  STG_B(0, 0, 0);
  STG_B(0, 1, 0);
  STG_A(1, 0, 64);
  STG_A(1, 1, 64);
  WAITV(4);
  BARR;

  // ---- main loop: iter it computes kt0=2it (buf0, P1-4), kt1 (buf1, P5-8) --
  for (int it = 0; it < 7; ++it) {
    const int kof = it * 128;  // u16 K-offset of kt0
    // P1: A(kh0,both ch) + B(kh0) reads; stage kt1 B-h0
    LDA_ALL(0, 0, 0);
    LDB_ALL(0, 0);
    LDA_ALL(1, 0, 0);
    STG_B(1, 0, kof + 64);
    BARR;
    MM(0, 0);
    BARR;
    // P2: A(kh1,both ch) reads; stage kt1 B-h1; drain lgkm (A region frees)
    LDA_ALL(0, 1, 0);
    LDA_ALL(1, 1, 0);
    STG_B(1, 1, kof + 64);
    BARR;
    MM(1, 0);
    WAITL;
    SCHED;
    BARR;
    // P3: B(kh1) reads; stage kt0+2 A-h0 (A region freed at P2 barrier)
    LDB_ALL(1, 0);
    STG_A(0, 0, kof + 128);
    BARR;
    MM(0, 1);
    BARR;
    // P4: stage kt0+2 A-h1; counted vmcnt: buf1 (kt1) fully landed
    STG_A(0, 1, kof + 128);
    BARR;
    MM(1, 1);
    WAITV(4);
    SCHED;
    BARR;
    // P5: buf1 reads; stage kt0+2 B-h0 (buf0 B freed at P4 barrier)
    LDA_ALL(0, 0, 1);
    LDB_ALL(0, 1);
    LDA_ALL(1, 0, 1);
    STG_B(0, 0, kof + 128);
    BARR;
    MM(0, 0);
    BARR;
    // P6: stage kt0+2 B-h1; drain lgkm (buf1 A region frees)
    LDA_ALL(0, 1, 1);
    LDA_ALL(1, 1, 1);
    STG_B(0, 1, kof + 128);
    BARR;
    MM(1, 0);
    WAITL;
    SCHED;
    BARR;
    // P7: stage kt1+2 A-h0
    LDB_ALL(1, 1);
    STG_A(1, 0, kof + 192);
    BARR;
    MM(0, 1);
    BARR;
    // P8: stage kt1+2 A-h1; counted vmcnt: buf0 (kt0+2) fully landed
    STG_A(1, 1, kof + 192);
    BARR;
    MM(1, 1);
    WAITV(4);
    SCHED;
    BARR;
  }

  // ---- peeled last iteration: kt14 (buf0), kt15 (buf1); stage kt15 B only --
  {
    LDA_ALL(0, 0, 0);
    LDB_ALL(0, 0);
    LDA_ALL(1, 0, 0);
    LDA_ALL(0, 1, 0);
    LDA_ALL(1, 1, 0);
    LDB_ALL(1, 0);
    STG_B(1, 0, 960);
    STG_B(1, 1, 960);
    MM(0, 0);
    MM(1, 0);
    MM(0, 1);
    MM(1, 1);
    WAITV(0);
    BARR;
    LDA_ALL(0, 0, 1);
    LDB_ALL(0, 1);
    LDA_ALL(1, 0, 1);
    LDA_ALL(0, 1, 1);
    LDA_ALL(1, 1, 1);
    LDB_ALL(1, 1);
    MM(0, 0);
    MM(1, 0);
    MM(0, 1);
    MM(1, 1);
  }

  // ---- epilogue ----
  if constexpr (MODE == 0) {
    const int q = n0 >> 10;  // 0=Q,1=K,2=V
    const int nb = (n0 & 1023) + wn * 64;
    const void* bp = (q == 0) ? b0 : ((q == 1) ? b1 : b2);
    u16* q0 = (u16*)o0;
#pragma unroll
    for (int ch = 0; ch < 2; ++ch)
#pragma unroll
      for (int fi = 0; fi < 4; ++fi) {
        const int mbase = m0 + wm * 128 + ch * 64 + fi * 16;  // mult of 16
        const int bidx = mbase >> 4;
#pragma unroll
        for (int bj = 0; bj < 4; ++bj) {
          const int nl = nb + bj * 16 + fr;
          const int h = nl >> 6, d = nl & 63;
          const float bias = ld_bias(bp, nl, isf32);
          const int bh = bidx * 16 + h;
          if (q == 2) {
            u16x4 pk;
#pragma unroll
            for (int r = 0; r < 4; ++r) pk[r] = f2bf(ACC(ch, fi, bj)[r] + bias);
            *reinterpret_cast<u16x4*>(&o2[(bh * 64 + d) * 16 + fq * 4]) = pk;
          } else {
            u16* dstq = (q == 0) ? q0 : o1;
#pragma unroll
            for (int r = 0; r < 4; ++r)
              dstq[(bh * 16 + fq * 4 + r) * 64 + d] =
                  f2bf(ACC(ch, fi, bj)[r] + bias);
          }
        }
      }
  } else {
#pragma unroll
    for (int ch = 0; ch < 2; ++ch)
#pragma unroll
      for (int fi = 0; fi < 4; ++fi) {
        const int m = m0 + wm * 128 + ch * 64 + fi * 16 + fq * 4;
#pragma unroll
        for (int bj = 0; bj < 4; ++bj) {
          const int n = n0 + wn * 64 + bj * 16 + fr;
          const float bias = ld_bias(b0, n, isf32);
          if (isf32) {
#pragma unroll
            for (int r = 0; r < 4; ++r)
              ((float*)o0)[(m + r) * 1024 + n] = ACC(ch, fi, bj)[r] + bias;
          } else {
#pragma unroll
            for (int r = 0; r < 4; ++r)
              ((u16*)o0)[(m + r) * 1024 + n] = f2bf(ACC(ch, fi, bj)[r] + bias);
          }
        }
      }
  }
#undef ACC
#undef STG_A
#undef STG_B
#undef LDA_ALL
#undef LDB_ALL
#undef MM1
#undef MM
#undef BARR
#undef WAITV
#undef WAITL
#undef SCHED
}

// ---------------- attention: one wave per (b,h), transposed chain ------------
// All operand transforms are register shuffles (c2frag), no LDS round-trips.
// Mt accumulation packs 2 irreps per MFMA (K=16+16): lanes<32 irrep p,
// lanes>=32 irrep p+1; MFMA's K-sum fuses the pair (Mt is a sum over p).
__global__ __launch_bounds__(256) void attn_kernel(
    const u16* __restrict__ Qb, const u16* __restrict__ Kb, const u16* __restrict__ Vt,
    const void* __restrict__ P, u16* __restrict__ Tb,
    const int* __restrict__ flag) {
  __shared__ alignas(16) u16 Pl[4096];   // P[p][i][j]
  __shared__ alignas(16) u16 Ptl[4096];  // P^T
  const int tid = threadIdx.x;
  const int isf32 = *flag;
#pragma unroll
  for (int i = 0; i < 16; ++i) {
    const int idx = i * 256 + tid;
    const u16 v = isf32 ? f2bf(((const float*)P)[idx]) : ((const u16*)P)[idx];
    Pl[idx] = v;
    const int p = idx >> 8, rc = idx & 255, rr = rc >> 4, cc = rc & 15;
    Ptl[(p << 8) + (cc << 4) + rr] = v;
  }
  __syncthreads();

  const int wave = tid >> 6, lane = tid & 63;
  const int bh = blockIdx.x * 4 + wave;
  const int fr = lane & 15, fq = lane >> 4;

  const u16* qb = Qb + bh * 1024;
  const u16* kb = Kb + bh * 1024;
  const u16* vb = Vt + bh * 1024;

  const bf16x8 qf0 = ld_frag(qb + fr * 64 + fq * 8);
  const bf16x8 qf1 = ld_frag(qb + fr * 64 + 32 + fq * 8);
  const bf16x8 kf0 = ld_frag(kb + fr * 64 + fq * 8);
  const bf16x8 kf1 = ld_frag(kb + fr * 64 + 32 + fq * 8);
  f32x4 S = {0.f, 0.f, 0.f, 0.f};
  S = MFMA16(qf0, kf0, S);
  S = MFMA16(qf1, kf1, S);
#pragma unroll
  for (int r = 0; r < 4; ++r) S[r] *= 0.125f;  // 1/sqrt(64)
  const bf16x8 St = c2frag(S, lane);  // S^T as A-operand, reused all irreps

  f32x4 Mt = {0.f, 0.f, 0.f, 0.f};
#pragma unroll 2
  for (int p = 0; p < 16; p += 2) {
    f32x4 z = {0.f, 0.f, 0.f, 0.f};
    // irrep p
    const bf16x8 plA = ld_frag_lo(Pl + (p << 8) + fr * 16 + fq * 8, lane);
    const f32x4 ApTA = MFMA16(St, plA, z);                  // (P_p S)^T
    const f32x4 BpTA = MFMA16(plA, c2frag(ApTA, lane), z);  // scores^T
    // irrep p+1
    const bf16x8 plB = ld_frag_lo(Pl + ((p + 1) << 8) + fr * 16 + fq * 8, lane);
    const f32x4 ApTB = MFMA16(St, plB, z);
    const f32x4 BpTB = MFMA16(plB, c2frag(ApTB, lane), z);
    // softmax both
    float eA[4], eB[4], sA = 0.f, sB = 0.f;
#pragma unroll
    for (int r = 0; r < 4; ++r) {
      eA[r] = __expf(BpTA[r]);
      sA += eA[r];
      eB[r] = __expf(BpTB[r]);
      sB += eB[r];
    }
    sA += __shfl_xor(sA, 16);
    sA += __shfl_xor(sA, 32);
    sB += __shfl_xor(sB, 16);
    sB += __shfl_xor(sB, 32);
    const float rsA = __frcp_rn(sA);
    const float rsB = __frcp_rn(sB);
    f32x4 wA, wB;
#pragma unroll
    for (int r = 0; r < 4; ++r) {
      wA[r] = eA[r] * rsA;
      wB[r] = eB[r] * rsB;
    }
    // packed accumulate: one MFMA covers both irreps (K=16+16)
    const bf16x8 ptP =
        ld_frag(Ptl + ((p + (fq >> 1)) << 8) + fr * 16 + (fq & 1) * 8);
    Mt = MFMA16(ptP, c2frag_pair(wA, wB, lane), Mt);  // (w P_p)^T + (w P_p+1)^T
  }

  const bf16x8 mb = c2frag(Mt, lane);  // M^T as B-operand

  const int b = bh >> 4, h = bh & 15;
  u16* outp = Tb + (b * 16 + fr) * 1024 + h * 64;  // fr = i (C-layout col)
#pragma unroll
  for (int dt = 0; dt < 4; ++dt) {
    const bf16x8 vf = ld_frag_lo(vb + (dt * 16 + fr) * 16 + fq * 8, lane);
    f32x4 z = {0.f, 0.f, 0.f, 0.f};
    const f32x4 ot = MFMA16(vf, mb, z);  // O^T tile: row=d, col=i
    u16x4 pk;
#pragma unroll
    for (int r = 0; r < 4; ++r) pk[r] = f2bf(ot[r]);
    *reinterpret_cast<u16x4*>(&outp[dt * 16 + fq * 4]) = pk;
  }
}

// ---------------- launcher ---------------------------------------------------
extern "C" void kernel_launch(void* const* d_in, const int* in_sizes, int n_in,
                              void* d_out, int out_size, void* d_ws, size_t ws_size,
                              hipStream_t stream) {
  const void* x = d_in[0];
  const void* proj = d_in[1];
  const void* Wq = d_in[2];
  const void* bq = d_in[3];
  const void* Wk = d_in[4];
  const void* bk = d_in[5];
  const void* Wv = d_in[6];
  const void* bv = d_in[7];
  const void* Wo = d_in[8];
  const void* bo = d_in[9];

  char* ws = (char*)d_ws;
  int* flag = (int*)ws;          ws += 256;
  u16* WtQKV = (u16*)ws;         ws += (size_t)3072 * 1024 * 2;
  u16* WtO   = (u16*)ws;         ws += (size_t)1024 * 1024 * 2;
  u16* Xb    = (u16*)ws;         ws += (size_t)16384 * 1024 * 2;
  u16* Qbuf  = (u16*)ws;         ws += (size_t)16384 * 1024 * 2;
  u16* Kbuf  = (u16*)ws;         ws += (size_t)16384 * 1024 * 2;
  u16* Vtb   = (u16*)ws;         ws += (size_t)16384 * 1024 * 2;
  u16* Tbuf  = (u16*)ws;         ws += (size_t)16384 * 1024 * 2;

  detect_dtype<<<1, 1024, 0, stream>>>((const u32*)x, flag);
  preprocess<<<20480, 256, 0, stream>>>(
      x, Xb, Wq, Wk, Wv, Wo, WtQKV, WtQKV + 1024 * 1024,
      WtQKV + 2 * 1024 * 1024, WtO, flag);

  // QKV GEMM: M=16384, N=3072 -> 64 x 12 = 768 blocks (768 % 8 == 0)
  gemm256<0><<<dim3(768), 512, 0, stream>>>(
      Xb, WtQKV, bq, bk, bv, Qbuf, Kbuf, Vtb, flag);
  attn_kernel<<<4096, 256, 0, stream>>>(Qbuf, Kbuf, Vtb, proj, Tbuf, flag);
  // out GEMM: M=16384, N=1024 -> 64 x 4 = 256 blocks
  gemm256<1><<<dim3(256), 512, 0, stream>>>(
      Tbuf, WtO, bo, nullptr, nullptr, d_out, nullptr, nullptr, flag);
}